// Round 2
// 1483.458 us; speedup vs baseline: 1.3490x; 1.3490x over previous
//
#include <hip/hip_runtime.h>

// EnhancedRWKVBlock on MI355X — round 4.
// Round-3 postmortem: NaN came from the ds_read swizzle using
//   col = s*32 + ((qd ^ (l16&7))*8)
// i.e. XOR over only the 2-bit qd with the k-slice added OUTSIDE the XOR,
// while staging swizzled the full 3-bit chunk index (c ^ (row&7)). For
// (l16&7)>=4, s=1 this read columns [64,96) of a 64-wide row -> OOB garbage.
// Fix: read chunk = ((s*4+qd) ^ (row&7)) over all 3 bits — store-side and
// read-side now apply the SAME involution (both-sides-or-neither, rule #21).
//
// Structure (unchanged from round 3): 256x256 8-phase pipelined GEMM
// (T1 XCD swizzle + T2 LDS XOR-swizzle + T3/T4 counted-vmcnt + T5 setprio).
//   BM=BN=256, BK=64, 512 thr = 8 waves (2M x 4N), per-wave C = 128x64.
//   LDS 128 KiB: 2 dbuf x [A 256x64 | B 256x64] bf16, halves of 128x64.
//   Per K-tile: 4 phases x 16 MFMA (2m x 4n x 2k). Phase 0 loads all B-frags.
//   Staging: ph0/ph1 -> A halves of tile t+1 (other buffer);
//            ph2/ph3 -> B halves of tile t+2 (this buffer's B region, dead
//            after this tile's phase-0 lgkmcnt+barrier).
//   vmcnt(4) once per K-tile (drains to 0 only at t>=NT-2).
// Grids: vkr 768, wo 256, kk 1024, vg 512 blocks — exact multiples of 256 CUs,
// all %8==0 for the bijective XCD swizzle.

typedef unsigned short u16;
typedef short short8 __attribute__((ext_vector_type(8)));
typedef float f32x4 __attribute__((ext_vector_type(4)));
typedef unsigned short u16x4 __attribute__((ext_vector_type(4)));

#define GAS(p) (const __attribute__((address_space(1))) void*)(p)
#define LAS(p) (__attribute__((address_space(3))) void*)(p)

__device__ __forceinline__ float bf2f(u16 h) { return __uint_as_float(((unsigned)h) << 16); }
__device__ __forceinline__ u16 f2bf(float f) {
  unsigned u = __float_as_uint(f);
  u += 0x7FFFu + ((u >> 16) & 1u);   // round-to-nearest-even
  return (u16)(u >> 16);
}
__device__ __forceinline__ float sigmoidf_(float x) { return 1.f / (1.f + expf(-x)); }

// ---------------------------------------------------------------- transpose+convert
// in: fp32 [R,C] row-major -> out bf16: out[(c*rs + ro)*R + r] = in[r*C + c].
__global__ __launch_bounds__(256) void transpose_bf16_kernel(
    const float* __restrict__ in, u16* __restrict__ out, int R, int C, int rs, int ro) {
  __shared__ float tile[32][33];
  const int cb = blockIdx.x * 32, rb = blockIdx.y * 32;
  const int tx = threadIdx.x, ty = threadIdx.y;  // (32,8)
#pragma unroll
  for (int i = 0; i < 32; i += 8)
    tile[ty + i][tx] = in[(size_t)(rb + ty + i) * C + (cb + tx)];
  __syncthreads();
#pragma unroll
  for (int i = 0; i < 32; i += 8)
    out[((size_t)(cb + ty + i) * rs + ro) * R + (rb + tx)] = f2bf(tile[tx][ty + i]);
}

// ---------------------------------------------------------------- LayerNorm (+optional lw softmax)
template <bool WITH_LW>
__global__ __launch_bounds__(256) void ln_kernel(
    const float* __restrict__ x, const float* __restrict__ sc, const float* __restrict__ bi,
    u16* __restrict__ hout,
    const float* __restrict__ lvlw, const float* __restrict__ lvlb,
    float* __restrict__ lwout) {
  const int tid = threadIdx.x;
  const int row = blockIdx.x;
  const int wv = tid >> 6, ln = tid & 63;
  const float* xr = x + (size_t)row * 2048;
  f32x4 a0 = *(const f32x4*)(xr + tid * 4);
  f32x4 a1 = *(const f32x4*)(xr + 1024 + tid * 4);
  float s = a0[0] + a0[1] + a0[2] + a0[3] + a1[0] + a1[1] + a1[2] + a1[3];
  float q = a0[0]*a0[0] + a0[1]*a0[1] + a0[2]*a0[2] + a0[3]*a0[3]
          + a1[0]*a1[0] + a1[1]*a1[1] + a1[2]*a1[2] + a1[3]*a1[3];
#pragma unroll
  for (int off = 32; off; off >>= 1) { s += __shfl_down(s, off); q += __shfl_down(q, off); }
  __shared__ float red[8];
  __shared__ float stats[2];
  if (ln == 0) { red[wv] = s; red[4 + wv] = q; }
  __syncthreads();
  if (tid == 0) {
    float S1 = red[0] + red[1] + red[2] + red[3];
    float S2 = red[4] + red[5] + red[6] + red[7];
    float m = S1 * (1.f / 2048.f);
    float var = S2 * (1.f / 2048.f) - m * m;
    stats[0] = m;
    stats[1] = rsqrtf(var + 1e-5f);
  }
  __syncthreads();
  const float m = stats[0], rs = stats[1];
  f32x4 s0 = *(const f32x4*)(sc + tid * 4), s1 = *(const f32x4*)(sc + 1024 + tid * 4);
  f32x4 b0 = *(const f32x4*)(bi + tid * 4), b1 = *(const f32x4*)(bi + 1024 + tid * 4);
  float h0[4], h1[4];
  u16x4 o0, o1;
#pragma unroll
  for (int e = 0; e < 4; e++) {
    h0[e] = (a0[e] - m) * rs * s0[e] + b0[e];
    h1[e] = (a1[e] - m) * rs * s1[e] + b1[e];
    o0[e] = f2bf(h0[e]);
    o1[e] = f2bf(h1[e]);
  }
  u16* hr = hout + (size_t)row * 2048;
  *(u16x4*)(hr + tid * 4) = o0;
  *(u16x4*)(hr + 1024 + tid * 4) = o1;

  if constexpr (WITH_LW) {
    f32x4 acc = (f32x4){0.f, 0.f, 0.f, 0.f};
#pragma unroll
    for (int e = 0; e < 4; e++)
      acc += (*(const f32x4*)(lvlw + (size_t)(tid * 4 + e) * 4)) * h0[e];
#pragma unroll
    for (int e = 0; e < 4; e++)
      acc += (*(const f32x4*)(lvlw + (size_t)(1024 + tid * 4 + e) * 4)) * h1[e];
#pragma unroll
    for (int off = 32; off; off >>= 1) {
      acc[0] += __shfl_down(acc[0], off);
      acc[1] += __shfl_down(acc[1], off);
      acc[2] += __shfl_down(acc[2], off);
      acc[3] += __shfl_down(acc[3], off);
    }
    __shared__ float red4[16];
    if (ln == 0) {
      red4[wv * 4 + 0] = acc[0]; red4[wv * 4 + 1] = acc[1];
      red4[wv * 4 + 2] = acc[2]; red4[wv * 4 + 3] = acc[3];
    }
    __syncthreads();
    if (tid == 0) {
      float lg[4];
#pragma unroll
      for (int d = 0; d < 4; d++)
        lg[d] = red4[d] + red4[4 + d] + red4[8 + d] + red4[12 + d] + lvlb[d];
      float mx = fmaxf(fmaxf(lg[0], lg[1]), fmaxf(lg[2], lg[3]));
      float e0 = expf(lg[0] - mx), e1 = expf(lg[1] - mx), e2 = expf(lg[2] - mx), e3 = expf(lg[3] - mx);
      float inv = 1.f / (e0 + e1 + e2 + e3);
      float* lr = lwout + (size_t)row * 4;
      lr[0] = e0 * inv; lr[1] = e1 * inv; lr[2] = e2 * inv; lr[3] = e3 * inv;
    }
  }
}

// ---------------------------------------------------------------- attention mix
__global__ __launch_bounds__(256) void mix_u_kernel(
    const u16* __restrict__ v, const u16* __restrict__ k, const u16* __restrict__ r,
    const float* __restrict__ lw, const float* __restrict__ att, const float* __restrict__ td,
    u16* __restrict__ u) {
  const size_t i4 = ((size_t)blockIdx.x * 256 + threadIdx.x) * 4;
  const int row = (int)(i4 >> 11);
  const int hh = (int)(i4 & 2047);
  const int b = row >> 11;
  f32x4 lwv = *(const f32x4*)(lw + (size_t)row * 4);
  u16x4 k_ = *(const u16x4*)(k + i4);
  u16x4 v_ = *(const u16x4*)(v + i4);
  u16x4 r_ = *(const u16x4*)(r + i4);
  f32x4 kv, acc = (f32x4){0.f, 0.f, 0.f, 0.f};
#pragma unroll
  for (int e = 0; e < 4; e++) kv[e] = bf2f(k_[e]) * bf2f(v_[e]);
#pragma unroll
  for (int d = 0; d < 4; d++) {
    f32x4 as_ = *(const f32x4*)(att + (size_t)(b * 4 + d) * 2048 + hh);
    f32x4 tdv = *(const f32x4*)(td + (size_t)d * 2048 + hh);
#pragma unroll
    for (int e = 0; e < 4; e++)
      acc[e] += lwv[d] * (as_[e] * expf(-expf(tdv[e])) + kv[e]);
  }
  u16x4 o;
#pragma unroll
  for (int e = 0; e < 4; e++) o[e] = f2bf(bf2f(r_[e]) * acc[e]);
  *(u16x4*)(u + i4) = o;
}

// ---------------------------------------------------------------- token shift mix
__global__ __launch_bounds__(256) void shift_mix_kernel(
    const u16* __restrict__ h2, const float* __restrict__ cm, const float* __restrict__ tmk,
    u16* __restrict__ km) {
  const size_t i4 = ((size_t)blockIdx.x * 256 + threadIdx.x) * 4;
  const int hh = (int)(i4 & 2047);
  const int row = (int)(i4 >> 11);
  const int b = row >> 11;
  const int t = row & 2047;
  f32x4 tk = *(const f32x4*)(tmk + hh);
  u16x4 cur_ = *(const u16x4*)(h2 + i4);
  f32x4 prev;
  if (t == 0) {
    prev = *(const f32x4*)(cm + (size_t)b * 2048 + hh);
  } else {
    u16x4 p_ = *(const u16x4*)(h2 + i4 - 2048);
#pragma unroll
    for (int e = 0; e < 4; e++) prev[e] = bf2f(p_[e]);
  }
  u16x4 o;
#pragma unroll
  for (int e = 0; e < 4; e++) {
    float c = bf2f(cur_[e]);
    o[e] = f2bf(c * tk[e] + prev[e] * (1.f - tk[e]));
  }
  *(u16x4*)(km + i4) = o;
}

// ---------------------------------------------------------------- 256^2 8-phase GEMM
// C[M,N] = A[M,K] @ Bt[N,K]^T, bf16 in, epilogue variants.
enum { EPI_ADDX = 0, EPI_RELU2, EPI_VKR, EPI_VG };

// Stage one 128x64 half-tile: 2 global_load_lds x (512 thr x 16B).
// LDS dest is linear (base + lane*16); the XOR swizzle chunk^=(row&7) is
// applied to the GLOBAL source column instead (rule #21), so ds_read applies
// the same XOR on its address and sees logical row-major data.
#define STAGE(srcrow_, hoff_, dbase_, kc_) do {                                   \
    const u16* g_ = (srcrow_) + (kc_);                                            \
    u16* d_ = (dbase_);                                                           \
    __builtin_amdgcn_global_load_lds(GAS(g_ + (size_t)(hoff_) * 2 * rj64), LAS(d_), 16, 0, 0);          \
    __builtin_amdgcn_global_load_lds(GAS(g_ + (size_t)(hoff_) * 2 * rj64 + rj64), LAS(d_ + 4096), 16, 0, 0); \
  } while (0)

template <int EPI>
__global__ __launch_bounds__(512, 2) void gemm256(
    const u16* __restrict__ A, const u16* __restrict__ Bt,
    void* o0, void* o1, void* o2, const float* __restrict__ aux_f,
    int M, int N, int K) {
  __shared__ __align__(16) u16 lds[65536];  // 128 KiB: 2 buf x [A 256x64 | B 256x64]
  const int tid = threadIdx.x;
  const int wave = tid >> 6, lane = tid & 63;
  const int qd = lane >> 4, l16 = lane & 15;
  const int wm = wave >> 2, wn = wave & 3;   // 2M x 4N wave grid
  (void)M;

  // ---- T1: bijective XCD swizzle (all grids here are %8 == 0) ----
  const int nbx = gridDim.x;
  const int nwg = nbx * gridDim.y;
  const int lin = blockIdx.y * nbx + blockIdx.x;
  const int cpx = nwg >> 3;
  const int swz = (lin & 7) * cpx + (lin >> 3);
  const int by = swz / nbx, bx = swz - by * nbx;
  const int brow = by << 8, bcol = bx << 8;

  // ---- staging addressing (call 0 covers rows 0..63 of a half, call 1 +64) ----
  const int r0 = tid >> 3;                                        // per-half row
  const int cswz = (((tid & 7) ^ (r0 & 7)) << 3);                 // pre-swizzled col (elems)
  const size_t rj64 = (size_t)64 * K;
  const u16* Arow = A + (size_t)(brow + r0) * K + cswz;
  const u16* Brow = Bt + (size_t)(bcol + r0) * K + cswz;
  u16* const dstw = lds + wave * 512;       // wave-uniform LDS base (u16 elems)
  // dest element bases: A half h of buf b: b*32768 + h*8192 ; B: +16384
#define DA(b_, h_) (dstw + (b_) * 32768 + (h_) * 8192)
#define DB(b_, h_) (dstw + (b_) * 32768 + 16384 + (h_) * 8192)

  // ---- ds_read addressing: chunk = ((s*4+qd) ^ (row&7)), row&7 == l16&7 ----
  // (round-3 bug: XOR covered only qd; the s-slice bit must be inside the XOR)
  const int r7 = l16 & 7;
  const int cS0 = ((qd) ^ r7) << 3;        // elems, k-slice s=0 (chunks 0..3 pre-swz)
  const int cS1 = ((4 + qd) ^ r7) << 3;    // elems, k-slice s=1 (chunks 4..7 pre-swz)
  const u16* ldsA = lds + wm * 8192 + l16 * 64;
  const u16* ldsB = lds + 16384 + (wn >> 1) * 8192 + ((wn & 1) * 64 + l16) * 64;

  f32x4 acc[8][4];
#pragma unroll
  for (int i = 0; i < 8; i++)
#pragma unroll
    for (int n = 0; n < 4; n++) acc[i][n] = (f32x4){0.f, 0.f, 0.f, 0.f};

  // ---- prologue: tile 0 (A+B) and tile 1 (B only) ----
  STAGE(Arow, 0, DA(0, 0), 0);
  STAGE(Arow, 1, DA(0, 1), 0);
  STAGE(Brow, 0, DB(0, 0), 0);
  STAGE(Brow, 1, DB(0, 1), 0);
  STAGE(Brow, 0, DB(1, 0), 64);
  STAGE(Brow, 1, DB(1, 1), 64);
  asm volatile("s_waitcnt vmcnt(4)" ::: "memory");  // tile 0 landed; B(1) in flight
  __builtin_amdgcn_s_barrier();

  const int NT = K >> 6;
  for (int t = 0; t < NT; ++t) {
    const int b = t & 1, nb = b ^ 1;
    const int kc1 = (t + 1) << 6, kc2 = (t + 2) << 6;
    const u16* lA = ldsA + b * 32768;
    const u16* lB = ldsB + b * 32768;
    short8 bfr[4][2];
#pragma unroll
    for (int g = 0; g < 4; ++g) {
      // --- phase g: ds-read register subtile ---
      if (g == 0) {
#pragma unroll
        for (int n = 0; n < 4; ++n) {
          bfr[n][0] = *(const short8*)(lB + n * 1024 + cS0);
          bfr[n][1] = *(const short8*)(lB + n * 1024 + cS1);
        }
      }
      short8 af[2][2];
#pragma unroll
      for (int mm = 0; mm < 2; ++mm) {
        af[mm][0] = *(const short8*)(lA + (g * 2 + mm) * 1024 + cS0);
        af[mm][1] = *(const short8*)(lA + (g * 2 + mm) * 1024 + cS1);
      }
      // --- stage one half-tile (liveness-ledger safe; see header) ---
      if (g == 0) { if (t + 1 < NT) STAGE(Arow, 0, DA(nb, 0), kc1); }
      else if (g == 1) { if (t + 1 < NT) STAGE(Arow, 1, DA(nb, 1), kc1); }
      else if (g == 2) { if (t + 2 < NT) STAGE(Brow, 0, DB(b, 0), kc2); }
      else             { if (t + 2 < NT) STAGE(Brow, 1, DB(b, 1), kc2); }
      // --- barrier / drain ds / MFMA cluster ---
      __builtin_amdgcn_s_barrier();
      asm volatile("s_waitcnt lgkmcnt(0)" ::: "memory");
      __builtin_amdgcn_sched_barrier(0);
      __builtin_amdgcn_s_setprio(1);
#pragma unroll
      for (int mm = 0; mm < 2; ++mm)
#pragma unroll
        for (int n = 0; n < 4; ++n)
#pragma unroll
          for (int s = 0; s < 2; ++s)
            acc[g * 2 + mm][n] = __builtin_amdgcn_mfma_f32_16x16x32_bf16(
                af[mm][s], bfr[n][s], acc[g * 2 + mm][n], 0, 0, 0);
      __builtin_amdgcn_s_setprio(0);
      if (g == 3) {  // counted vmcnt once per K-tile; drains only at the tail
        if (t < NT - 2) asm volatile("s_waitcnt vmcnt(4)" ::: "memory");
        else            asm volatile("s_waitcnt vmcnt(0)" ::: "memory");
      }
      __builtin_amdgcn_s_barrier();
    }
  }

  // ---- epilogue: C/D layout row = qd*4+rg, col = l16 (verified mapping) ----
  const int rw = brow + wm * 128 + qd * 4;
  const int cw = bcol + wn * 64 + l16;
#pragma unroll
  for (int i = 0; i < 8; ++i)
#pragma unroll
    for (int n = 0; n < 4; ++n)
#pragma unroll
      for (int rg = 0; rg < 4; ++rg) {
        const int rr = rw + i * 16 + rg;
        const int cc = cw + n * 16;
        const float vv = acc[i][n][rg];
        if constexpr (EPI == EPI_ADDX) {
          const size_t idx = (size_t)rr * N + cc;
          ((float*)o0)[idx] = vv + aux_f[idx];
        } else if constexpr (EPI == EPI_RELU2) {
          const size_t idx = (size_t)rr * N + cc;
          float tt = vv > 0.f ? vv : 0.f;
          ((u16*)o0)[idx] = f2bf(tt * tt);
        } else if constexpr (EPI == EPI_VKR) {
          // N=6144 = [v|k|r]; 256-wide blocks never straddle a 2048 boundary
          const int seg = cc >> 11, local = cc & 2047;
          const size_t idx = (size_t)rr * 2048 + local;
          if (seg == 0)      ((u16*)o0)[idx] = f2bf(vv);
          else if (seg == 1) ((u16*)o1)[idx] = f2bf(vv);
          else               ((u16*)o2)[idx] = f2bf(sigmoidf_(vv));
        } else {  // EPI_VG: Bt rows interleaved (even=Wval col, odd=Wgate col)
          const float part = __shfl_xor(vv, 1);  // partner lane: same out col, other matrix
          if ((l16 & 1) == 0) {
            const size_t idx = (size_t)rr * 2048 + (size_t)(cc >> 1);
            ((float*)o0)[idx] = aux_f[idx] + vv * sigmoidf_(part);
          }
        }
      }
#undef DA
#undef DB
}

// ---------------------------------------------------------------- launch
extern "C" void kernel_launch(void* const* d_in, const int* in_sizes, int n_in,
                              void* d_out, int out_size, void* d_ws, size_t ws_size,
                              hipStream_t stream) {
  const float* x = (const float*)d_in[0];
  const float* att_state = (const float*)d_in[1];
  const float* cm_state = (const float*)d_in[2];
  const float* ln1_s = (const float*)d_in[3];
  const float* ln1_b = (const float*)d_in[4];
  const float* ln2_s = (const float*)d_in[5];
  const float* ln2_b = (const float*)d_in[6];
  const float* td = (const float*)d_in[7];
  const float* lvl_w = (const float*)d_in[8];
  const float* lvl_b = (const float*)d_in[9];
  const float* Wv = (const float*)d_in[10];
  const float* Wk = (const float*)d_in[11];
  const float* Wr = (const float*)d_in[12];
  const float* Wo = (const float*)d_in[13];
  const float* tmk = (const float*)d_in[14];
  const float* Wkey = (const float*)d_in[15];
  const float* Wval = (const float*)d_in[16];
  const float* Wgate = (const float*)d_in[17];
  float* out = (float*)d_out;

  const size_t S = 8192ull * 2048ull;     // B*T*H
  const size_t S4 = 8192ull * 8192ull;    // B*T*FF
  char* ws = (char*)d_ws;
  u16* bufW = (u16*)(ws);                 // slot0 32MB: Bt for vkr(24MB)/Wo(8MB)/Wkey(32MB)
  u16* hbuf = (u16*)(ws + 1 * S * 2);     // slot1: h, then u
  u16* vbuf = (u16*)(ws + 2 * S * 2);     // slot2: v, then h2
  u16* kbuf = (u16*)(ws + 3 * S * 2);     // slot3: k, then km
  u16* rbuf = (u16*)(ws + 4 * S * 2);     // slot4: r
  u16* bufVG = hbuf;                      // slot1+2 (64MB): interleaved [Wval|Wgate]^T, after u/h2 die
  u16* kkbuf = (u16*)(ws + 5 * S * 2);    // 128MB: kk
  float* lwbuf = (float*)(ws + 5 * S * 2 + S4 * 2);  // 128KB: lw
  (void)in_sizes; (void)n_in; (void)out_size; (void)ws_size;

  const dim3 tb256(256);
  const dim3 tb512(512);
  const dim3 ttb(32, 8);
  const dim3 gT2k(64, 64);                 // 2048x2048 transpose
  const dim3 gTkey(256, 64);               // Wkey [2048,8192]
  const dim3 gTvg(64, 256);                // Wval/Wgate [8192,2048]
  const dim3 gemm_vkr(6144 / 256, 32);     // 24x32 = 768 blocks (3 full CU waves)
  const dim3 gemm_wo(2048 / 256, 32);      // 8x32  = 256 blocks (1 wave)
  const dim3 gemm_kk(8192 / 256, 32);      // 32x32 = 1024 blocks (4 waves)
  const dim3 gemm_vg(4096 / 256, 32);      // 16x32 = 512 blocks (2 waves)
  const int elemBlocks = (int)(S / 1024);

  // ln1 -> h (bf16) + lw softmax
  ln_kernel<true><<<8192, tb256, 0, stream>>>(x, ln1_s, ln1_b, hbuf, lvl_w, lvl_b, lwbuf);
  // Bt = [Wv^T ; Wk^T ; Wr^T] rows 0..6143
  transpose_bf16_kernel<<<gT2k, ttb, 0, stream>>>(Wv, bufW, 2048, 2048, 1, 0);
  transpose_bf16_kernel<<<gT2k, ttb, 0, stream>>>(Wk, bufW, 2048, 2048, 1, 2048);
  transpose_bf16_kernel<<<gT2k, ttb, 0, stream>>>(Wr, bufW, 2048, 2048, 1, 4096);
  // [v|k|r] fused GEMM
  gemm256<EPI_VKR><<<gemm_vkr, tb512, 0, stream>>>(hbuf, bufW, vbuf, kbuf, rbuf, nullptr, 8192, 6144, 2048);
  // u -> hbuf (h dead)
  mix_u_kernel<<<elemBlocks, tb256, 0, stream>>>(vbuf, kbuf, rbuf, lwbuf, att_state, td, hbuf);
  // x1 = x + u@Wo -> d_out (fp32)
  transpose_bf16_kernel<<<gT2k, ttb, 0, stream>>>(Wo, bufW, 2048, 2048, 1, 0);
  gemm256<EPI_ADDX><<<gemm_wo, tb512, 0, stream>>>(hbuf, bufW, out, nullptr, nullptr, x, 8192, 2048, 2048);
  // h2 = ln2(x1) -> vbuf (v dead)
  ln_kernel<false><<<8192, tb256, 0, stream>>>(out, ln2_s, ln2_b, vbuf, nullptr, nullptr, nullptr);
  // km -> kbuf (k dead)
  shift_mix_kernel<<<elemBlocks, tb256, 0, stream>>>(vbuf, cm_state, tmk, kbuf);
  // kk = relu(km@Wkey)^2 -> kkbuf
  transpose_bf16_kernel<<<gTkey, ttb, 0, stream>>>(Wkey, bufW, 2048, 8192, 1, 0);
  gemm256<EPI_RELU2><<<gemm_kk, tb512, 0, stream>>>(kbuf, bufW, kkbuf, nullptr, nullptr, nullptr, 8192, 8192, 2048);
  // interleaved [Wval|Wgate]^T into slot1+2 (u, h2 dead now)
  transpose_bf16_kernel<<<gTvg, ttb, 0, stream>>>(Wval, bufVG, 8192, 2048, 2, 0);
  transpose_bf16_kernel<<<gTvg, ttb, 0, stream>>>(Wgate, bufVG, 8192, 2048, 2, 1);
  // out = x1 + (kk@Wval)*sigmoid(kk@Wgate), fused, in-place on d_out
  gemm256<EPI_VG><<<gemm_vg, tb512, 0, stream>>>(kkbuf, bufVG, out, nullptr, nullptr, out, 8192, 4096, 8192);
}